// Round 9
// baseline (258.419 us; speedup 1.0000x reference)
//
#include <hip/hip_runtime.h>
#include <math.h>

// NSA attention (round 21: seltopk3 rank-scan. Round 20 post-mortem: ballot
// binary search kept a ~1300cy strictly-serial v_cmp->s_bcnt->s_cselect
// chain (44+8 steps); dur unchanged at ~76 us, VALU 45% -- still latency-
// bound. Fix: the exact top-16 needs NO search. With cnt (~18-24, >=16
// guaranteed) candidates, write all cnt unique 44-bit ordinals
// ((f2o(s)^0x80000000)<<12 | 2047-key = exact jax (val desc, key asc) order)
// to LDS; each candidate lane scans them (broadcast ds_read_b64, unroll-4,
// parallel across lanes, no serial chain) computing rank = #{ord_y > mine}.
// Uniqueness => ranks are a permutation => winners are EXACTLY rank<16 and
// rank IS the output slot (no winner-compaction ballots). 8-step u8
// threshold search + compaction + epilogue verbatim from r19/r20 (verified).
// Rest of pipeline = r19 (251 us): MFMA u8 screen panel, exact recompute.
// B=2 L=2048 C=256 H=8 HD=32 BS=16 SK=16 win=+-32.

#define Bc 2
#define Lc 2048
#define Cc 256
#define Hc 8
#define HDc 32
#define BHc 16          // B*H
#define NBc 128         // L/BS
#define ROWSc 4096      // B*L
#define TROWSc 32768    // B*H*L
#define SCALEc 0.17677669529663687f

typedef unsigned long long u64;
typedef __attribute__((ext_vector_type(8))) short short8v;   // 8 bf16
typedef __attribute__((ext_vector_type(4))) float f32x4;

// ---------- helpers ----------

__device__ __forceinline__ float dot32q(const float* qr, const float* kr) {
  const float4* k4 = (const float4*)kr;
  float p0 = 0.f, p1 = 0.f, p2 = 0.f, p3 = 0.f;
#pragma unroll
  for (int j = 0; j < 8; j += 4) {
    float4 a = k4[j], b = k4[j + 1], c = k4[j + 2], e = k4[j + 3];
    p0 += a.x * qr[4 * j + 0] + a.y * qr[4 * j + 1] + a.z * qr[4 * j + 2] + a.w * qr[4 * j + 3];
    p1 += b.x * qr[4 * j + 4] + b.y * qr[4 * j + 5] + b.z * qr[4 * j + 6] + b.w * qr[4 * j + 7];
    p2 += c.x * qr[4 * j + 8] + c.y * qr[4 * j + 9] + c.z * qr[4 * j + 10] + c.w * qr[4 * j + 11];
    p3 += e.x * qr[4 * j + 12] + e.y * qr[4 * j + 13] + e.z * qr[4 * j + 14] + e.w * qr[4 * j + 15];
  }
  return (p0 + p1) + (p2 + p3);
}

__device__ __forceinline__ unsigned short bf16rne(float f) {
  const unsigned u = __float_as_uint(f);
  return (unsigned short)((u + 0x7fffu + ((u >> 16) & 1u)) >> 16);
}

// order-preserving float->int map
__device__ __forceinline__ int f2o(float x) {
  const int i = __float_as_int(x);
  return i >= 0 ? i : (i ^ 0x7fffffff);
}

// ---------- projections ----------
// X(4096,256) @ W(256,256) + bias. headlayout=1: store [b*H+h][l][d]; else [row][c].
__global__ __launch_bounds__(256) void proj_kernel(const float* __restrict__ X,
                                                   const float* __restrict__ W,
                                                   const float* __restrict__ bias,
                                                   float* __restrict__ outp, int headlayout) {
  __shared__ float xs[8 * Cc];
  const int tid = threadIdx.x;
  const int row0 = blockIdx.x * 8;
  {
    const float4* xin = (const float4*)(X + (size_t)row0 * Cc);
    float4* xsv = (float4*)xs;
    xsv[tid] = xin[tid];
    xsv[tid + 256] = xin[tid + 256];
  }
  __syncthreads();
  const int c0 = (tid & 63) * 4;  // 4 consecutive cols
  const int rh = tid >> 6;        // wave id; 2 rows per wave
  float acc[2][4];
#pragma unroll
  for (int r = 0; r < 2; ++r)
#pragma unroll
    for (int c = 0; c < 4; ++c) acc[r][c] = 0.f;

#pragma unroll 4
  for (int d4 = 0; d4 < 64; ++d4) {
    const int d = d4 * 4;
    const float4 w0 = *(const float4*)(W + (size_t)(d + 0) * Cc + c0);
    const float4 w1 = *(const float4*)(W + (size_t)(d + 1) * Cc + c0);
    const float4 w2 = *(const float4*)(W + (size_t)(d + 2) * Cc + c0);
    const float4 w3 = *(const float4*)(W + (size_t)(d + 3) * Cc + c0);
#pragma unroll
    for (int r = 0; r < 2; ++r) {
      const float4 xv = *(const float4*)(xs + (rh * 2 + r) * Cc + d);
      acc[r][0] += xv.x * w0.x + xv.y * w1.x + xv.z * w2.x + xv.w * w3.x;
      acc[r][1] += xv.x * w0.y + xv.y * w1.y + xv.z * w2.y + xv.w * w3.y;
      acc[r][2] += xv.x * w0.z + xv.y * w1.z + xv.z * w2.z + xv.w * w3.z;
      acc[r][3] += xv.x * w0.w + xv.y * w1.w + xv.z * w2.w + xv.w * w3.w;
    }
  }
  const float4 bv = *(const float4*)(bias + c0);
#pragma unroll
  for (int r = 0; r < 2; ++r) {
    const int grow = row0 + rh * 2 + r;
    const float4 o = make_float4(acc[r][0] + bv.x, acc[r][1] + bv.y,
                                 acc[r][2] + bv.z, acc[r][3] + bv.w);
    if (headlayout) {
      const int b = grow >> 11, l = grow & 2047;
      const int h = c0 >> 5, dd = c0 & 31;
      *(float4*)(outp + (((size_t)(b * Hc + h) * Lc + l) * HDc + dd)) = o;
    } else {
      *(float4*)(outp + (size_t)grow * Cc + c0) = o;
    }
  }
}

// gate = sigmoid(query @ Wg + bg), one thread per row
__global__ __launch_bounds__(256) void gate_kernel(const float* __restrict__ query,
                                                   const float* __restrict__ Wg,
                                                   const float* __restrict__ bg,
                                                   float* __restrict__ gatep) {
  const int row = blockIdx.x * 256 + threadIdx.x;
  const float4* x4 = (const float4*)(query + (size_t)row * Cc);
  float a0 = bg[0], a1 = bg[1], a2 = bg[2];
#pragma unroll 8
  for (int d4 = 0; d4 < 64; ++d4) {
    const float4 xv = x4[d4];
    const float* wr = Wg + d4 * 12;
    a0 += xv.x * wr[0] + xv.y * wr[3] + xv.z * wr[6] + xv.w * wr[9];
    a1 += xv.x * wr[1] + xv.y * wr[4] + xv.z * wr[7] + xv.w * wr[10];
    a2 += xv.x * wr[2] + xv.y * wr[5] + xv.z * wr[8] + xv.w * wr[11];
  }
  float* g = gatep + (size_t)row * 3;
  g[0] = 1.f / (1.f + __expf(-a0));
  g[1] = 1.f / (1.f + __expf(-a1));
  g[2] = 1.f / (1.f + __expf(-a2));
}

// ---------- compressed K/V ----------
__global__ __launch_bounds__(256) void cmpkv_kernel(const float* __restrict__ kh,
                                                    const float* __restrict__ vh,
                                                    const float* __restrict__ WKc,
                                                    const float* __restrict__ WVc,
                                                    const float* __restrict__ Wpe,
                                                    float* __restrict__ Kcp,
                                                    float* __restrict__ Vcp) {
  const int idx = blockIdx.x * 256 + threadIdx.x;  // 65536 = bh*128*32
  const int d = idx & 31, n = (idx >> 5) & 127, bh = idx >> 12;
  float pk = 0.f, pv = 0.f;
#pragma unroll
  for (int s = 0; s < 16; ++s) {
    const float pe = Wpe[s * Cc + d];
    pk += pe * WKc[s];
    pv += pe * WVc[s];
  }
  const float* kp = kh + ((size_t)bh * Lc + n * 16) * HDc + d;
  const float* vp = vh + ((size_t)bh * Lc + n * 16) * HDc + d;
  float ak = pk, av = pv;
#pragma unroll
  for (int s = 0; s < 16; ++s) {
    ak += kp[s * HDc] * WKc[s];
    av += vp[s * HDc] * WVc[s];
  }
  Kcp[idx] = ak;
  Vcp[idx] = av;
}

// ---------- compressed attention ----------
__global__ __launch_bounds__(512) void cmp_attn_kernel(const float* __restrict__ qh,
                                                       const float* __restrict__ Kcp,
                                                       const float* __restrict__ Vcp,
                                                       float* __restrict__ ocmp) {
  __shared__ float sc[128][65];
  __shared__ float pm[8][64];
  const int tid = threadIdx.x, lane = tid & 63;
  const int w = __builtin_amdgcn_readfirstlane(tid >> 6);
  const int bh = blockIdx.y;
  const int lrow = blockIdx.x * 64 + lane;
  const float* q = qh + ((size_t)bh * Lc + lrow) * HDc;
  float qr[HDc];
#pragma unroll
  for (int d = 0; d < HDc; ++d) qr[d] = q[d] * SCALEc;
  const float* kcb = Kcp + (size_t)bh * NBc * HDc;
  float pmax = -1e30f;
#pragma unroll
  for (int i = 0; i < 16; ++i) {
    const int key = w * 16 + i;  // uniform
    const float s = dot32q(qr, kcb + (size_t)key * HDc);
    sc[key][lane] = s;
    pmax = fmaxf(pmax, s);
  }
  pm[w][lane] = pmax;
  __syncthreads();

  const int row = tid >> 3;        // 0..63
  const int dg = (tid & 7) * 4;    // dim-group base
  float m = pm[0][row];
#pragma unroll
  for (int i = 1; i < 8; ++i) m = fmaxf(m, pm[i][row]);
  const float* vcb = Vcp + (size_t)bh * NBc * HDc + dg;
  float o0 = 0.f, o1 = 0.f, o2 = 0.f, o3 = 0.f, z = 0.f;
#pragma unroll 4
  for (int key = 0; key < 128; ++key) {
    const float wgt = __expf(sc[key][row] - m);
    z += wgt;
    const float4 v = *(const float4*)(vcb + key * HDc);
    o0 += wgt * v.x; o1 += wgt * v.y; o2 += wgt * v.z; o3 += wgt * v.w;
  }
  const float iz = 1.f / z;
  *(float4*)(ocmp + ((size_t)bh * Lc + blockIdx.x * 64 + row) * HDc + dg) =
      make_float4(o0 * iz, o1 * iz, o2 * iz, o3 * iz);
}

// ---------- f32 -> bf16 (rne) for qh, kh ----------
__global__ __launch_bounds__(256) void cvtbf16_kernel(const float* __restrict__ qh,
                                                      const float* __restrict__ kh,
                                                      unsigned short* __restrict__ qhb,
                                                      unsigned short* __restrict__ khb) {
  const int gid = blockIdx.x * 256 + threadIdx.x;  // 0..524288
  const int half = (TROWSc * HDc) / 4;             // 262144 float4-groups
  const float* src = gid < half ? qh : kh;
  unsigned short* dst = gid < half ? qhb : khb;
  const int i = (gid < half ? gid : gid - half) * 4;
  const float4 v = *(const float4*)(src + i);
  ushort4 o;
  o.x = bf16rne(v.x);
  o.y = bf16rne(v.y);
  o.z = bf16rne(v.z);
  o.w = bf16rne(v.w);
  *(ushort4*)(dst + i) = o;
}

// ---------- MFMA screening panel ----------
// Grid (128 rowtiles, 4 keychunks, 16 heads), block 256 = 4 waves. Wave w:
// rows [r0,r0+16) x keys [chunk*512 + w*128, +128) = 8 MFMA 16x16x32 (K=32 =
// HD in one shot). Fragments: lane l: m/n = l&15, g = l>>4, elems = dims
// [8g,8g+8) -> ONE coalesced 16B global load per operand (mirrored-slot
// cancellation makes the HW k-map irrelevant). D (m89-verified): lane holds
// rows 4g+r, col l&15. Quantize u8 (monotone trunc map), per-wave LDS
// transpose tile [16][136], coalesced 128B-row global stores. No barriers.
__global__ __launch_bounds__(256) void mfma_panel_kernel(
    const unsigned short* __restrict__ qhb,
    const unsigned short* __restrict__ khb,
    unsigned char* __restrict__ panel) {
  __shared__ unsigned char lp[4][16][136];
  const int tid = threadIdx.x, lane = tid & 63;
  const int w = tid >> 6;
  const int g = lane >> 4;
  const int mn = lane & 15;
  const int bh = blockIdx.z;
  const int r0 = blockIdx.x * 16;
  const int k0 = blockIdx.y * 512 + w * 128;

  const short8v qa =
      *(const short8v*)(qhb + ((size_t)bh * Lc + r0 + mn) * HDc + g * 8);
  const unsigned short* kbase = khb + ((size_t)bh * Lc + k0) * HDc + g * 8;

  f32x4 acc0 = {0.f, 0.f, 0.f, 0.f}, acc1 = acc0, acc2 = acc0, acc3 = acc0;
  f32x4 acc4 = acc0, acc5 = acc0, acc6 = acc0, acc7 = acc0;
#define MM(i, dstv)                                                            \
  {                                                                            \
    const short8v kb = *(const short8v*)(kbase + (size_t)((i)*16 + mn) * HDc); \
    dstv = __builtin_amdgcn_mfma_f32_16x16x32_bf16(qa, kb, dstv, 0, 0, 0);     \
  }
  MM(0, acc0) MM(1, acc1) MM(2, acc2) MM(3, acc3)
  MM(4, acc4) MM(5, acc5) MM(6, acc6) MM(7, acc7)
#undef MM

#define QSTORE(t, accv)                                                        \
  {                                                                            \
    _Pragma("unroll") for (int r = 0; r < 4; ++r) {                            \
      const float s = accv[r] * SCALEc;                                        \
      int qi = (int)(s * 16.f + 128.f);                                        \
      qi = qi < 0 ? 0 : (qi > 255 ? 255 : qi);                                 \
      lp[w][4 * g + r][(t)*16 + mn] = (unsigned char)qi;                       \
    }                                                                          \
  }
  QSTORE(0, acc0) QSTORE(1, acc1) QSTORE(2, acc2) QSTORE(3, acc3)
  QSTORE(4, acc4) QSTORE(5, acc5) QSTORE(6, acc6) QSTORE(7, acc7)
#undef QSTORE
  __asm__ volatile("s_waitcnt lgkmcnt(0)" ::: "memory");

  // store: 2 iterations; per inst 8 lanes cover one full 128B panel row.
#pragma unroll
  for (int i = 0; i < 2; ++i) {
    const int row = i * 8 + (lane >> 3);
    const int kb8 = (lane & 7) * 16;
    const unsigned long long lo = *(const unsigned long long*)&lp[w][row][kb8];
    const unsigned long long hi =
        *(const unsigned long long*)&lp[w][row][kb8 + 8];
    uint4 o;
    o.x = (unsigned)lo;
    o.y = (unsigned)(lo >> 32);
    o.z = (unsigned)hi;
    o.w = (unsigned)(hi >> 32);
    *(uint4*)(panel + ((size_t)bh * Lc + r0 + row) * Lc + k0 + kb8) = o;
  }
}

// ---------- selection: u8 screen -> exact recompute -> top-16 + softmax+V --
// One wave per row, rank-scan edition:
//  1. per-lane max of its 32 u8 (coalesced 32B loads)
//  2. M16q = 16th-largest lane max via 8-step ballot binary search; thr =
//     M16q - 5 (bf16+quant margin, r19-verified superset); cnt >= 16
//  3. ballot-compact candidate keys (cnt in [16,128], cap 128)
//  4. recompute exact f32 dots for slots {lane, lane+64}; pack 44-bit unique
//     ordinals (f2o<<12 | 2047-key) = exact jax (val desc, key asc) order
//  5. ordinals -> LDS; each candidate lane scans all cnt ordinals (broadcast
//     ds_read_b64, parallel across lanes, NO serial chain): rank = #{> mine}.
//     Uniqueness => ranks a permutation => winners EXACTLY rank<16, rank =
//     output slot (no compaction ballots).
//  6. softmax (mtop = fmax chain) + V gather.
__global__ __launch_bounds__(256) void seltopk3_kernel(const unsigned char* __restrict__ panel,
                                                       const float* __restrict__ qh,
                                                       const float* __restrict__ kh,
                                                       const float* __restrict__ vh,
                                                       float* __restrict__ oslc) {
  __shared__ float candv[4][16];
  __shared__ unsigned candk[4][128];
  __shared__ u64 ords[4][128];
  const int wave = threadIdx.x >> 6, lane = threadIdx.x & 63;
  const int r = blockIdx.x * 4 + wave;  // global row = bh*Lc + l
  const int bh = r >> 11;
  const int l = r & 2047;

  // ---- 1. load my 32 q's (32 contiguous bytes), per-lane max ----
  const uint4* p4 = (const uint4*)(panel + (size_t)r * Lc);
  const uint4 pa = p4[2 * lane], pb = p4[2 * lane + 1];
  unsigned wds[8] = {pa.x, pa.y, pa.z, pa.w, pb.x, pb.y, pb.z, pb.w};
  int q[32];
#pragma unroll
  for (int wi = 0; wi < 8; ++wi) {
    q[4 * wi + 0] = (int)(wds[wi] & 255u);
    q[4 * wi + 1] = (int)((wds[wi] >> 8) & 255u);
    q[4 * wi + 2] = (int)((wds[wi] >> 16) & 255u);
    q[4 * wi + 3] = (int)(wds[wi] >> 24);
  }
  int mq = 0;
#pragma unroll
  for (int i = 0; i < 32; ++i) mq = max(mq, q[i]);

  // ---- 2. M16q via 8-step ballot binary search (u8 domain) ----
  int T8 = 0;
#pragma unroll
  for (int b = 7; b >= 0; --b) {
    const int trial = T8 | (1 << b);
    const int c = (int)__popcll(__ballot(mq >= trial));
    if (c >= 16) T8 = trial;  // wave-uniform
  }
  const int thr = T8 - 5;  // margin: bf16 screen err + quant bucket

  // ---- 3. pad slots, ballot-compact candidate keys (q >= thr) ----
  candk[wave][lane] = 0x7fffffffu;
  candk[wave][64 + lane] = 0x7fffffffu;
  __asm__ volatile("s_waitcnt lgkmcnt(0)" ::: "memory");
  int base = 0;
#pragma unroll
  for (int i = 0; i < 32; ++i) {
    const bool p_ = q[i] >= thr;
    const unsigned long long bm_ = __ballot(p_);
    if (bm_) {
      if (p_) {
        const int pos_ = base + (int)__builtin_amdgcn_mbcnt_hi(
                                    (unsigned)(bm_ >> 32),
                                    __builtin_amdgcn_mbcnt_lo((unsigned)bm_, 0u));
        if (pos_ < 128) candk[wave][pos_] = (unsigned)(lane * 32 + i);
      }
      base += (int)__popcll(bm_);
    }
  }
  const int cnt = base < 128 ? base : 128;  // wave-uniform, >= 16
  __asm__ volatile("s_waitcnt lgkmcnt(0)" ::: "memory");

  // ---- 4. recompute exact f32 dots for slots {lane, lane+64} ----
  const float* qp = qh + (size_t)r * HDc;
  float qr[HDc];
#pragma unroll
  for (int d = 0; d < HDc; ++d) qr[d] = qp[d] * SCALEc;
  const float* kb = kh + (size_t)bh * Lc * HDc;

  const bool vA = (lane < cnt);
  const bool vB = (64 + lane < cnt);
  const unsigned kA = candk[wave][lane];
  const unsigned kB = candk[wave][64 + lane];
  const float sA = dot32q(qr, kb + (size_t)(vA ? kA : 0u) * HDc);
  const float sB = dot32q(qr, kb + (size_t)(vB ? kB : 0u) * HDc);
  const u64 ordA =
      vA ? (((u64)((unsigned)f2o(sA) ^ 0x80000000u) << 12) | (u64)(2047u - kA))
         : 0ull;
  const u64 ordB =
      vB ? (((u64)((unsigned)f2o(sB) ^ 0x80000000u) << 12) | (u64)(2047u - kB))
         : 0ull;

  // ---- 5. rank scan (no serial chain) ----
  ords[wave][lane] = ordA;
  ords[wave][64 + lane] = ordB;
  __asm__ volatile("s_waitcnt lgkmcnt(0)" ::: "memory");
  int rankA = 0, rankB = 0;
#pragma unroll 4
  for (int i = 0; i < cnt; ++i) {  // wave-uniform trip count (~18 typ.)
    const u64 o = ords[wave][i];   // same addr all lanes -> LDS broadcast
    rankA += (o > ordA) ? 1 : 0;
    rankB += (o > ordB) ? 1 : 0;
  }
  // winners: valid && rank<16; rank is the output slot (unique permutation)
  if (vA && rankA < 16) {
    candv[wave][rankA] = sA;
    candk[wave][rankA] = kA;
  }
  if (vB && rankB < 16) {
    candv[wave][rankB] = sB;
    candk[wave][rankB] = kB;
  }
  __asm__ volatile("s_waitcnt lgkmcnt(0)" ::: "memory");

  // ---- 6. softmax + V gather (order-invariant; mtop = fmax chain) ----
  float mtop = candv[wave][0];
#pragma unroll
  for (int i = 1; i < 16; ++i) mtop = fmaxf(mtop, candv[wave][i]);
  const int d = lane & 31;
  const float* vb = vh + (size_t)bh * Lc * HDc + d;
  float z = 0.f, oacc = 0.f;
#pragma unroll
  for (int i = 0; i < 16; ++i) {
    const float w_ = __expf(candv[wave][i] - mtop);
    z += w_;
    oacc += w_ * vb[(size_t)candk[wave][i] * HDc];
  }
  if (lane < 32) oslc[((size_t)bh * Lc + l) * HDc + d] = oacc / z;
}

// ---------- window attention (±32 band) ----------
__global__ __launch_bounds__(512) void win_attn_kernel(const float* __restrict__ qh,
                                                       const float* __restrict__ kh,
                                                       const float* __restrict__ vh,
                                                       float* __restrict__ owin) {
  __shared__ float sc[128][65];
  __shared__ float pm[8][64];
  const int tid = threadIdx.x, lane = tid & 63;
  const int w = __builtin_amdgcn_readfirstlane(tid >> 6);
  const int bh = blockIdx.y;
  const int l0 = blockIdx.x * 64;
  const int lrow = l0 + lane;
  const float* q = qh + ((size_t)bh * Lc + lrow) * HDc;
  float qr[HDc];
#pragma unroll
  for (int d = 0; d < HDc; ++d) qr[d] = q[d] * SCALEc;
  const float* kb = kh + (size_t)bh * Lc * HDc;
  float pmax = -1e30f;
#pragma unroll
  for (int i = 0; i < 16; ++i) {
    const int j = w * 16 + i;            // 0..127 (uniform)
    const int key = l0 - 32 + j;         // absolute key (uniform)
    const int keyc = min(max(key, 0), Lc - 1);  // uniform clamp for the load
    float s = dot32q(qr, kb + (size_t)keyc * HDc);
    const int delta = key - lrow;        // lane-varying
    const bool ok = (key >= 0) && (key < Lc) && (delta >= -32) && (delta <= 32);
    s = ok ? s : -1e30f;
    sc[j][lane] = s;
    pmax = fmaxf(pmax, s);
  }
  pm[w][lane] = pmax;
  __syncthreads();

  const int row = tid >> 3;
  const int dg = (tid & 7) * 4;
  float m = pm[0][row];
#pragma unroll
  for (int i = 1; i < 8; ++i) m = fmaxf(m, pm[i][row]);
  const float* vb = vh + (size_t)bh * Lc * HDc + dg;
  float o0 = 0.f, o1 = 0.f, o2 = 0.f, o3 = 0.f, z = 0.f;
#pragma unroll 4
  for (int j = 0; j < 128; ++j) {
    const float wgt = __expf(sc[j][row] - m);  // 0 for masked entries
    z += wgt;
    const int keyc = min(max(l0 - 32 + j, 0), Lc - 1);
    const float4 v = *(const float4*)(vb + (size_t)keyc * HDc);
    o0 += wgt * v.x; o1 += wgt * v.y; o2 += wgt * v.z; o3 += wgt * v.w;
  }
  const float iz = 1.f / z;
  *(float4*)(owin + ((size_t)bh * Lc + l0 + row) * HDc + dg) =
      make_float4(o0 * iz, o1 * iz, o2 * iz, o3 * iz);
}

// ---------- gated combine into merged (B,L,C) ----------
__global__ __launch_bounds__(256) void combine_kernel(const float* __restrict__ ocmp,
                                                      const float* __restrict__ oslc,
                                                      const float* __restrict__ owin,
                                                      const float* __restrict__ gatep,
                                                      float* __restrict__ xm) {
  const int idx = blockIdx.x * 256 + threadIdx.x;  // 4096 rows * 64 float4-groups
  const int c4 = idx & 63, grow = idx >> 6;
  const int b = grow >> 11, l = grow & 2047;
  const int h = c4 >> 3, d4 = (c4 & 7) * 4;
  const size_t hoff = (((size_t)(b * Hc + h) * Lc + l)) * HDc + d4;
  const float g0 = gatep[(size_t)grow * 3 + 0];
  const float g1 = gatep[(size_t)grow * 3 + 1];
  const float g2 = gatep[(size_t)grow * 3 + 2];
  const float4 a = *(const float4*)(ocmp + hoff);
  const float4 s = *(const float4*)(oslc + hoff);
  const float4 w = *(const float4*)(owin + hoff);
  float4 r;
  r.x = g0 * a.x + g1 * s.x + g2 * w.x;
  r.y = g0 * a.y + g1 * s.y + g2 * w.y;
  r.z = g0 * a.z + g1 * s.z + g2 * w.z;
  r.w = g0 * a.w + g1 * s.w + g2 * w.w;
  *(float4*)(xm + (size_t)grow * Cc + c4 * 4) = r;
}

// ---------- launch ----------
extern "C" void kernel_launch(void* const* d_in, const int* in_sizes, int n_in,
                              void* d_out, int out_size, void* d_ws, size_t ws_size,
                              hipStream_t stream) {
  (void)in_sizes; (void)n_in; (void)out_size; (void)ws_size;
  const float* query = (const float*)d_in[0];
  const float* key   = (const float*)d_in[1];
  const float* value = (const float*)d_in[2];
  const float* Wq = (const float*)d_in[3];
  const float* bq = (const float*)d_in[4];
  const float* Wk = (const float*)d_in[5];
  const float* bk = (const float*)d_in[6];
  const float* Wv = (const float*)d_in[7];
  const float* bv = (const float*)d_in[8];
  const float* Wo = (const float*)d_in[9];
  const float* bo = (const float*)d_in[10];
  const float* WKc = (const float*)d_in[11];
  const float* WVc = (const float*)d_in[12];
  const float* Wpe = (const float*)d_in[13];
  const float* Wg = (const float*)d_in[14];
  const float* bg = (const float*)d_in[15];

  size_t off = 0;
  auto alloc = [&](size_t bytes) -> void* {
    void* p = (char*)d_ws + off;
    off += (bytes + 255) & ~(size_t)255;
    return p;
  };
  float* qh    = (float*)alloc((size_t)TROWSc * HDc * 4);
  float* kh    = (float*)alloc((size_t)TROWSc * HDc * 4);
  float* vh    = (float*)alloc((size_t)TROWSc * HDc * 4);
  float* gatep = (float*)alloc((size_t)ROWSc * 3 * 4);
  float* Kcp   = (float*)alloc((size_t)BHc * NBc * HDc * 4);
  float* Vcp   = (float*)alloc((size_t)BHc * NBc * HDc * 4);
  float* ocmp  = (float*)alloc((size_t)TROWSc * HDc * 4);
  float* oslc  = (float*)alloc((size_t)TROWSc * HDc * 4);
  float* owin  = (float*)alloc((size_t)TROWSc * HDc * 4);
  float* xm    = (float*)alloc((size_t)ROWSc * Cc * 4);
  unsigned short* qhb = (unsigned short*)alloc((size_t)TROWSc * HDc * 2);
  unsigned short* khb = (unsigned short*)alloc((size_t)TROWSc * HDc * 2);
  unsigned char* panel = (unsigned char*)alloc((size_t)TROWSc * Lc);  // 67 MB

  proj_kernel<<<dim3(512), 256, 0, stream>>>(query, Wq, bq, qh, 1);
  proj_kernel<<<dim3(512), 256, 0, stream>>>(key, Wk, bk, kh, 1);
  proj_kernel<<<dim3(512), 256, 0, stream>>>(value, Wv, bv, vh, 1);
  gate_kernel<<<dim3(16), 256, 0, stream>>>(query, Wg, bg, gatep);
  cmpkv_kernel<<<dim3(256), 256, 0, stream>>>(kh, vh, WKc, WVc, Wpe, Kcp, Vcp);
  cmp_attn_kernel<<<dim3(32, 16), 512, 0, stream>>>(qh, Kcp, Vcp, ocmp);
  cvtbf16_kernel<<<dim3(2048), 256, 0, stream>>>(qh, kh, qhb, khb);
  mfma_panel_kernel<<<dim3(128, 4, 16), 256, 0, stream>>>(qhb, khb, panel);
  seltopk3_kernel<<<dim3(TROWSc / 4), 256, 0, stream>>>(panel, qh, kh, vh, oslc);
  win_attn_kernel<<<dim3(32, 16), 512, 0, stream>>>(qh, kh, vh, owin);
  combine_kernel<<<dim3(1024), 256, 0, stream>>>(ocmp, oslc, owin, gatep, xm);
  proj_kernel<<<dim3(512), 256, 0, stream>>>(xm, Wo, bo, (float*)d_out, 0);
}

// Round 10
// 249.144 us; speedup vs baseline: 1.0372x; 1.0372x over previous
//
#include <hip/hip_runtime.h>
#include <math.h>

// NSA attention (round 22: panel+selection fused; panel lives in LDS only.
// Round 19/20/21 post-mortem: three seltopk3 variants with ~2x different
// selection instruction counts all landed at 72-76 us -> bound by the shared
// 67 MB panel HBM round trip (read @ ~900 GB/s effective, latency-exposed at
// 37% occupancy), not by top-k machinery. A 16x2048 u8 panel is 32 KB: one
// 512-thread block computes it in LDS (phase A = r19's VERIFIED MFMA
// fragment code, 16 MFMA/wave over its 256-key chunk, QSTORE -> padded lp
// tile -> 16B copies into pnl[16][2064]) and consumes it (phase B = r21's
// VERIFIED selection: 8-step u8 ballot threshold, -5 margin, ballot-compact,
// exact f32 recompute, rank-scan, softmax+V; 2 rows/wave) after ONE barrier.
// Deletes: 67 MB panel write + 61 MB read + a kernel launch. LDS 63 KB ->
// 2 blocks/CU; phase-B chains are now LDS/L2-only. Prior fusion failures
// don't apply (MFMA compute, no emission bookkeeping, <64KB LDS).
// B=2 L=2048 C=256 H=8 HD=32 BS=16 SK=16 win=+-32.

#define Bc 2
#define Lc 2048
#define Cc 256
#define Hc 8
#define HDc 32
#define BHc 16          // B*H
#define NBc 128         // L/BS
#define ROWSc 4096      // B*L
#define TROWSc 32768    // B*H*L
#define SCALEc 0.17677669529663687f

typedef unsigned long long u64;
typedef __attribute__((ext_vector_type(8))) short short8v;   // 8 bf16
typedef __attribute__((ext_vector_type(4))) float f32x4;

// ---------- helpers ----------

__device__ __forceinline__ float dot32q(const float* qr, const float* kr) {
  const float4* k4 = (const float4*)kr;
  float p0 = 0.f, p1 = 0.f, p2 = 0.f, p3 = 0.f;
#pragma unroll
  for (int j = 0; j < 8; j += 4) {
    float4 a = k4[j], b = k4[j + 1], c = k4[j + 2], e = k4[j + 3];
    p0 += a.x * qr[4 * j + 0] + a.y * qr[4 * j + 1] + a.z * qr[4 * j + 2] + a.w * qr[4 * j + 3];
    p1 += b.x * qr[4 * j + 4] + b.y * qr[4 * j + 5] + b.z * qr[4 * j + 6] + b.w * qr[4 * j + 7];
    p2 += c.x * qr[4 * j + 8] + c.y * qr[4 * j + 9] + c.z * qr[4 * j + 10] + c.w * qr[4 * j + 11];
    p3 += e.x * qr[4 * j + 12] + e.y * qr[4 * j + 13] + e.z * qr[4 * j + 14] + e.w * qr[4 * j + 15];
  }
  return (p0 + p1) + (p2 + p3);
}

__device__ __forceinline__ unsigned short bf16rne(float f) {
  const unsigned u = __float_as_uint(f);
  return (unsigned short)((u + 0x7fffu + ((u >> 16) & 1u)) >> 16);
}

// order-preserving float->int map
__device__ __forceinline__ int f2o(float x) {
  const int i = __float_as_int(x);
  return i >= 0 ? i : (i ^ 0x7fffffff);
}

// ---------- projections ----------
// X(4096,256) @ W(256,256) + bias. headlayout=1: store [b*H+h][l][d]; else [row][c].
__global__ __launch_bounds__(256) void proj_kernel(const float* __restrict__ X,
                                                   const float* __restrict__ W,
                                                   const float* __restrict__ bias,
                                                   float* __restrict__ outp, int headlayout) {
  __shared__ float xs[8 * Cc];
  const int tid = threadIdx.x;
  const int row0 = blockIdx.x * 8;
  {
    const float4* xin = (const float4*)(X + (size_t)row0 * Cc);
    float4* xsv = (float4*)xs;
    xsv[tid] = xin[tid];
    xsv[tid + 256] = xin[tid + 256];
  }
  __syncthreads();
  const int c0 = (tid & 63) * 4;  // 4 consecutive cols
  const int rh = tid >> 6;        // wave id; 2 rows per wave
  float acc[2][4];
#pragma unroll
  for (int r = 0; r < 2; ++r)
#pragma unroll
    for (int c = 0; c < 4; ++c) acc[r][c] = 0.f;

#pragma unroll 4
  for (int d4 = 0; d4 < 64; ++d4) {
    const int d = d4 * 4;
    const float4 w0 = *(const float4*)(W + (size_t)(d + 0) * Cc + c0);
    const float4 w1 = *(const float4*)(W + (size_t)(d + 1) * Cc + c0);
    const float4 w2 = *(const float4*)(W + (size_t)(d + 2) * Cc + c0);
    const float4 w3 = *(const float4*)(W + (size_t)(d + 3) * Cc + c0);
#pragma unroll
    for (int r = 0; r < 2; ++r) {
      const float4 xv = *(const float4*)(xs + (rh * 2 + r) * Cc + d);
      acc[r][0] += xv.x * w0.x + xv.y * w1.x + xv.z * w2.x + xv.w * w3.x;
      acc[r][1] += xv.x * w0.y + xv.y * w1.y + xv.z * w2.y + xv.w * w3.y;
      acc[r][2] += xv.x * w0.z + xv.y * w1.z + xv.z * w2.z + xv.w * w3.z;
      acc[r][3] += xv.x * w0.w + xv.y * w1.w + xv.z * w2.w + xv.w * w3.w;
    }
  }
  const float4 bv = *(const float4*)(bias + c0);
#pragma unroll
  for (int r = 0; r < 2; ++r) {
    const int grow = row0 + rh * 2 + r;
    const float4 o = make_float4(acc[r][0] + bv.x, acc[r][1] + bv.y,
                                 acc[r][2] + bv.z, acc[r][3] + bv.w);
    if (headlayout) {
      const int b = grow >> 11, l = grow & 2047;
      const int h = c0 >> 5, dd = c0 & 31;
      *(float4*)(outp + (((size_t)(b * Hc + h) * Lc + l) * HDc + dd)) = o;
    } else {
      *(float4*)(outp + (size_t)grow * Cc + c0) = o;
    }
  }
}

// gate = sigmoid(query @ Wg + bg), one thread per row
__global__ __launch_bounds__(256) void gate_kernel(const float* __restrict__ query,
                                                   const float* __restrict__ Wg,
                                                   const float* __restrict__ bg,
                                                   float* __restrict__ gatep) {
  const int row = blockIdx.x * 256 + threadIdx.x;
  const float4* x4 = (const float4*)(query + (size_t)row * Cc);
  float a0 = bg[0], a1 = bg[1], a2 = bg[2];
#pragma unroll 8
  for (int d4 = 0; d4 < 64; ++d4) {
    const float4 xv = x4[d4];
    const float* wr = Wg + d4 * 12;
    a0 += xv.x * wr[0] + xv.y * wr[3] + xv.z * wr[6] + xv.w * wr[9];
    a1 += xv.x * wr[1] + xv.y * wr[4] + xv.z * wr[7] + xv.w * wr[10];
    a2 += xv.x * wr[2] + xv.y * wr[5] + xv.z * wr[8] + xv.w * wr[11];
  }
  float* g = gatep + (size_t)row * 3;
  g[0] = 1.f / (1.f + __expf(-a0));
  g[1] = 1.f / (1.f + __expf(-a1));
  g[2] = 1.f / (1.f + __expf(-a2));
}

// ---------- compressed K/V ----------
__global__ __launch_bounds__(256) void cmpkv_kernel(const float* __restrict__ kh,
                                                    const float* __restrict__ vh,
                                                    const float* __restrict__ WKc,
                                                    const float* __restrict__ WVc,
                                                    const float* __restrict__ Wpe,
                                                    float* __restrict__ Kcp,
                                                    float* __restrict__ Vcp) {
  const int idx = blockIdx.x * 256 + threadIdx.x;  // 65536 = bh*128*32
  const int d = idx & 31, n = (idx >> 5) & 127, bh = idx >> 12;
  float pk = 0.f, pv = 0.f;
#pragma unroll
  for (int s = 0; s < 16; ++s) {
    const float pe = Wpe[s * Cc + d];
    pk += pe * WKc[s];
    pv += pe * WVc[s];
  }
  const float* kp = kh + ((size_t)bh * Lc + n * 16) * HDc + d;
  const float* vp = vh + ((size_t)bh * Lc + n * 16) * HDc + d;
  float ak = pk, av = pv;
#pragma unroll
  for (int s = 0; s < 16; ++s) {
    ak += kp[s * HDc] * WKc[s];
    av += vp[s * HDc] * WVc[s];
  }
  Kcp[idx] = ak;
  Vcp[idx] = av;
}

// ---------- compressed attention ----------
__global__ __launch_bounds__(512) void cmp_attn_kernel(const float* __restrict__ qh,
                                                       const float* __restrict__ Kcp,
                                                       const float* __restrict__ Vcp,
                                                       float* __restrict__ ocmp) {
  __shared__ float sc[128][65];
  __shared__ float pm[8][64];
  const int tid = threadIdx.x, lane = tid & 63;
  const int w = __builtin_amdgcn_readfirstlane(tid >> 6);
  const int bh = blockIdx.y;
  const int lrow = blockIdx.x * 64 + lane;
  const float* q = qh + ((size_t)bh * Lc + lrow) * HDc;
  float qr[HDc];
#pragma unroll
  for (int d = 0; d < HDc; ++d) qr[d] = q[d] * SCALEc;
  const float* kcb = Kcp + (size_t)bh * NBc * HDc;
  float pmax = -1e30f;
#pragma unroll
  for (int i = 0; i < 16; ++i) {
    const int key = w * 16 + i;  // uniform
    const float s = dot32q(qr, kcb + (size_t)key * HDc);
    sc[key][lane] = s;
    pmax = fmaxf(pmax, s);
  }
  pm[w][lane] = pmax;
  __syncthreads();

  const int row = tid >> 3;        // 0..63
  const int dg = (tid & 7) * 4;    // dim-group base
  float m = pm[0][row];
#pragma unroll
  for (int i = 1; i < 8; ++i) m = fmaxf(m, pm[i][row]);
  const float* vcb = Vcp + (size_t)bh * NBc * HDc + dg;
  float o0 = 0.f, o1 = 0.f, o2 = 0.f, o3 = 0.f, z = 0.f;
#pragma unroll 4
  for (int key = 0; key < 128; ++key) {
    const float wgt = __expf(sc[key][row] - m);
    z += wgt;
    const float4 v = *(const float4*)(vcb + key * HDc);
    o0 += wgt * v.x; o1 += wgt * v.y; o2 += wgt * v.z; o3 += wgt * v.w;
  }
  const float iz = 1.f / z;
  *(float4*)(ocmp + ((size_t)bh * Lc + blockIdx.x * 64 + row) * HDc + dg) =
      make_float4(o0 * iz, o1 * iz, o2 * iz, o3 * iz);
}

// ---------- f32 -> bf16 (rne) for qh, kh ----------
__global__ __launch_bounds__(256) void cvtbf16_kernel(const float* __restrict__ qh,
                                                      const float* __restrict__ kh,
                                                      unsigned short* __restrict__ qhb,
                                                      unsigned short* __restrict__ khb) {
  const int gid = blockIdx.x * 256 + threadIdx.x;  // 0..524288
  const int half = (TROWSc * HDc) / 4;             // 262144 float4-groups
  const float* src = gid < half ? qh : kh;
  unsigned short* dst = gid < half ? qhb : khb;
  const int i = (gid < half ? gid : gid - half) * 4;
  const float4 v = *(const float4*)(src + i);
  ushort4 o;
  o.x = bf16rne(v.x);
  o.y = bf16rne(v.y);
  o.z = bf16rne(v.z);
  o.w = bf16rne(v.w);
  *(ushort4*)(dst + i) = o;
}

// ---------- fused MFMA screen panel (LDS) + selection ----------
// Grid (128 rowtiles, 16 heads), block 512 = 8 waves.
// Phase A (r19-verified fragments): wave w computes rows [r0,r0+16) x keys
// [w*256,+256) as 2 chunks x 8 MFMA 16x16x32 (lane l: m/n = l&15, g = l>>4,
// dims [8g,8g+8), ONE 16B load per operand; D: lane holds rows 4g+r, col
// l&15). Quantize u8 (monotone), QSTORE -> lp[w][16][136] transpose tile,
// 16B copies into pnl[16][2064] (pad 2064 -> per-row bank shift 4).
// ONE barrier.
// Phase B (r21-verified): wave w rows {2w, 2w+1}: 32 u8/lane from pnl;
// 8-step ballot threshold (M16q - 5 margin, provable superset);
// ballot-compact keys; exact f32 recompute; 44-bit-ordinal rank scan
// (exact jax (val desc, key asc)); softmax + V gather.
__global__ __launch_bounds__(512) void mfma_sel_kernel(
    const unsigned short* __restrict__ qhb,
    const unsigned short* __restrict__ khb,
    const float* __restrict__ qh,
    const float* __restrict__ kh,
    const float* __restrict__ vh,
    float* __restrict__ oslc) {
  __shared__ unsigned char pnl[16][2064];   // 33,024 B (pad: bank shift 4/row)
  __shared__ unsigned char lp[8][16][136];  // 17,408 B
  __shared__ float candv[8][16];
  __shared__ unsigned candk[8][128];
  __shared__ u64 ords[8][128];
  const int tid = threadIdx.x, lane = tid & 63;
  const int w = __builtin_amdgcn_readfirstlane(tid >> 6);
  const int g = lane >> 4;
  const int mn = lane & 15;
  const int bh = blockIdx.y;
  const int r0 = blockIdx.x * 16;

  // ---- phase A: u8 panel -> LDS ----
  const short8v qa =
      *(const short8v*)(qhb + ((size_t)bh * Lc + r0 + mn) * HDc + g * 8);
#pragma unroll
  for (int it = 0; it < 2; ++it) {
    const int k0 = w * 256 + it * 128;
    const unsigned short* kbase = khb + ((size_t)bh * Lc + k0) * HDc + g * 8;
    f32x4 acc0 = {0.f, 0.f, 0.f, 0.f}, acc1 = acc0, acc2 = acc0, acc3 = acc0;
    f32x4 acc4 = acc0, acc5 = acc0, acc6 = acc0, acc7 = acc0;
#define MM(i, dstv)                                                            \
  {                                                                            \
    const short8v kb = *(const short8v*)(kbase + (size_t)((i)*16 + mn) * HDc); \
    dstv = __builtin_amdgcn_mfma_f32_16x16x32_bf16(qa, kb, dstv, 0, 0, 0);     \
  }
    MM(0, acc0) MM(1, acc1) MM(2, acc2) MM(3, acc3)
    MM(4, acc4) MM(5, acc5) MM(6, acc6) MM(7, acc7)
#undef MM
#define QSTORE(t, accv)                                                        \
  {                                                                            \
    _Pragma("unroll") for (int r = 0; r < 4; ++r) {                            \
      const float s = accv[r] * SCALEc;                                        \
      int qi = (int)(s * 16.f + 128.f);                                        \
      qi = qi < 0 ? 0 : (qi > 255 ? 255 : qi);                                 \
      lp[w][4 * g + r][(t)*16 + mn] = (unsigned char)qi;                       \
    }                                                                          \
  }
    QSTORE(0, acc0) QSTORE(1, acc1) QSTORE(2, acc2) QSTORE(3, acc3)
    QSTORE(4, acc4) QSTORE(5, acc5) QSTORE(6, acc6) QSTORE(7, acc7)
#undef QSTORE
    __asm__ volatile("s_waitcnt lgkmcnt(0)" ::: "memory");
    // copy lp[w] -> pnl rows (16B per lane; 8 rows x 8 col-groups per iter)
#pragma unroll
    for (int i = 0; i < 2; ++i) {
      const int row = i * 8 + (lane >> 3);
      const int kb8 = (lane & 7) * 16;
      const uint4 v = *(const uint4*)&lp[w][row][kb8];
      *(uint4*)&pnl[row][k0 + kb8] = v;
    }
    __asm__ volatile("s_waitcnt lgkmcnt(0)" ::: "memory");
  }
  __syncthreads();

  // ---- phase B: selection for rows 2w, 2w+1 ----
#pragma unroll 1
  for (int rr = 0; rr < 2; ++rr) {
    const int row = w * 2 + rr;
    const int l = r0 + row;
    const int r = bh * Lc + l;  // global row

    // 1. 32 u8 from LDS panel, per-lane max
    const uint4 pa = *(const uint4*)&pnl[row][lane * 32];
    const uint4 pb = *(const uint4*)&pnl[row][lane * 32 + 16];
    unsigned wds[8] = {pa.x, pa.y, pa.z, pa.w, pb.x, pb.y, pb.z, pb.w};
    int q[32];
#pragma unroll
    for (int wi = 0; wi < 8; ++wi) {
      q[4 * wi + 0] = (int)(wds[wi] & 255u);
      q[4 * wi + 1] = (int)((wds[wi] >> 8) & 255u);
      q[4 * wi + 2] = (int)((wds[wi] >> 16) & 255u);
      q[4 * wi + 3] = (int)(wds[wi] >> 24);
    }
    int mq = 0;
#pragma unroll
    for (int i = 0; i < 32; ++i) mq = max(mq, q[i]);

    // 2. M16q via 8-step ballot binary search
    int T8 = 0;
#pragma unroll
    for (int b = 7; b >= 0; --b) {
      const int trial = T8 | (1 << b);
      const int c = (int)__popcll(__ballot(mq >= trial));
      if (c >= 16) T8 = trial;  // wave-uniform
    }
    const int thr = T8 - 5;  // margin: bf16 screen err + quant bucket

    // 3. ballot-compact candidate keys (q >= thr)
    candk[w][lane] = 0x7fffffffu;
    candk[w][64 + lane] = 0x7fffffffu;
    __asm__ volatile("s_waitcnt lgkmcnt(0)" ::: "memory");
    int base = 0;
#pragma unroll
    for (int i = 0; i < 32; ++i) {
      const bool p_ = q[i] >= thr;
      const unsigned long long bm_ = __ballot(p_);
      if (bm_) {
        if (p_) {
          const int pos_ =
              base + (int)__builtin_amdgcn_mbcnt_hi(
                         (unsigned)(bm_ >> 32),
                         __builtin_amdgcn_mbcnt_lo((unsigned)bm_, 0u));
          if (pos_ < 128) candk[w][pos_] = (unsigned)(lane * 32 + i);
        }
        base += (int)__popcll(bm_);
      }
    }
    const int cnt = base < 128 ? base : 128;  // wave-uniform, >= 16
    __asm__ volatile("s_waitcnt lgkmcnt(0)" ::: "memory");

    // 4. exact f32 dots for slots {lane, lane+64}; 44-bit unique ordinals
    const float* qp = qh + (size_t)r * HDc;
    float qr[HDc];
#pragma unroll
    for (int d = 0; d < HDc; ++d) qr[d] = qp[d] * SCALEc;
    const float* kb = kh + (size_t)bh * Lc * HDc;

    const bool vA = (lane < cnt);
    const bool vB = (64 + lane < cnt);
    const unsigned kA = candk[w][lane];
    const unsigned kB = candk[w][64 + lane];
    const float sA = dot32q(qr, kb + (size_t)(vA ? kA : 0u) * HDc);
    const float sB = dot32q(qr, kb + (size_t)(vB ? kB : 0u) * HDc);
    const u64 ordA =
        vA ? (((u64)((unsigned)f2o(sA) ^ 0x80000000u) << 12) | (u64)(2047u - kA))
           : 0ull;
    const u64 ordB =
        vB ? (((u64)((unsigned)f2o(sB) ^ 0x80000000u) << 12) | (u64)(2047u - kB))
           : 0ull;

    // 5. rank scan (parallel across lanes, no serial chain)
    ords[w][lane] = ordA;
    ords[w][64 + lane] = ordB;
    __asm__ volatile("s_waitcnt lgkmcnt(0)" ::: "memory");
    int rankA = 0, rankB = 0;
#pragma unroll 4
    for (int i = 0; i < cnt; ++i) {  // wave-uniform trip count
      const u64 o = ords[w][i];      // same addr all lanes -> LDS broadcast
      rankA += (o > ordA) ? 1 : 0;
      rankB += (o > ordB) ? 1 : 0;
    }
    if (vA && rankA < 16) {
      candv[w][rankA] = sA;
      candk[w][rankA] = kA;
    }
    if (vB && rankB < 16) {
      candv[w][rankB] = sB;
      candk[w][rankB] = kB;
    }
    __asm__ volatile("s_waitcnt lgkmcnt(0)" ::: "memory");

    // 6. softmax + V gather (order-invariant; mtop = fmax chain)
    float mtop = candv[w][0];
#pragma unroll
    for (int i = 1; i < 16; ++i) mtop = fmaxf(mtop, candv[w][i]);
    const int d = lane & 31;
    const float* vb = vh + (size_t)bh * Lc * HDc + d;
    float z = 0.f, oacc = 0.f;
#pragma unroll
    for (int i = 0; i < 16; ++i) {
      const float w_ = __expf(candv[w][i] - mtop);
      z += w_;
      oacc += w_ * vb[(size_t)candk[w][i] * HDc];
    }
    if (lane < 32) oslc[((size_t)bh * Lc + l) * HDc + d] = oacc / z;
  }
}

// ---------- window attention (±32 band) ----------
__global__ __launch_bounds__(512) void win_attn_kernel(const float* __restrict__ qh,
                                                       const float* __restrict__ kh,
                                                       const float* __restrict__ vh,
                                                       float* __restrict__ owin) {
  __shared__ float sc[128][65];
  __shared__ float pm[8][64];
  const int tid = threadIdx.x, lane = tid & 63;
  const int w = __builtin_amdgcn_readfirstlane(tid >> 6);
  const int bh = blockIdx.y;
  const int l0 = blockIdx.x * 64;
  const int lrow = l0 + lane;
  const float* q = qh + ((size_t)bh * Lc + lrow) * HDc;
  float qr[HDc];
#pragma unroll
  for (int d = 0; d < HDc; ++d) qr[d] = q[d] * SCALEc;
  const float* kb = kh + (size_t)bh * Lc * HDc;
  float pmax = -1e30f;
#pragma unroll
  for (int i = 0; i < 16; ++i) {
    const int j = w * 16 + i;            // 0..127 (uniform)
    const int key = l0 - 32 + j;         // absolute key (uniform)
    const int keyc = min(max(key, 0), Lc - 1);  // uniform clamp for the load
    float s = dot32q(qr, kb + (size_t)keyc * HDc);
    const int delta = key - lrow;        // lane-varying
    const bool ok = (key >= 0) && (key < Lc) && (delta >= -32) && (delta <= 32);
    s = ok ? s : -1e30f;
    sc[j][lane] = s;
    pmax = fmaxf(pmax, s);
  }
  pm[w][lane] = pmax;
  __syncthreads();

  const int row = tid >> 3;
  const int dg = (tid & 7) * 4;
  float m = pm[0][row];
#pragma unroll
  for (int i = 1; i < 8; ++i) m = fmaxf(m, pm[i][row]);
  const float* vb = vh + (size_t)bh * Lc * HDc + dg;
  float o0 = 0.f, o1 = 0.f, o2 = 0.f, o3 = 0.f, z = 0.f;
#pragma unroll 4
  for (int j = 0; j < 128; ++j) {
    const float wgt = __expf(sc[j][row] - m);  // 0 for masked entries
    z += wgt;
    const int keyc = min(max(l0 - 32 + j, 0), Lc - 1);
    const float4 v = *(const float4*)(vb + (size_t)keyc * HDc);
    o0 += wgt * v.x; o1 += wgt * v.y; o2 += wgt * v.z; o3 += wgt * v.w;
  }
  const float iz = 1.f / z;
  *(float4*)(owin + ((size_t)bh * Lc + l0 + row) * HDc + dg) =
      make_float4(o0 * iz, o1 * iz, o2 * iz, o3 * iz);
}

// ---------- gated combine into merged (B,L,C) ----------
__global__ __launch_bounds__(256) void combine_kernel(const float* __restrict__ ocmp,
                                                      const float* __restrict__ oslc,
                                                      const float* __restrict__ owin,
                                                      const float* __restrict__ gatep,
                                                      float* __restrict__ xm) {
  const int idx = blockIdx.x * 256 + threadIdx.x;  // 4096 rows * 64 float4-groups
  const int c4 = idx & 63, grow = idx >> 6;
  const int b = grow >> 11, l = grow & 2047;
  const int h = c4 >> 3, d4 = (c4 & 7) * 4;
  const size_t hoff = (((size_t)(b * Hc + h) * Lc + l)) * HDc + d4;
  const float g0 = gatep[(size_t)grow * 3 + 0];
  const float g1 = gatep[(size_t)grow * 3 + 1];
  const float g2 = gatep[(size_t)grow * 3 + 2];
  const float4 a = *(const float4*)(ocmp + hoff);
  const float4 s = *(const float4*)(oslc + hoff);
  const float4 w = *(const float4*)(owin + hoff);
  float4 r;
  r.x = g0 * a.x + g1 * s.x + g2 * w.x;
  r.y = g0 * a.y + g1 * s.y + g2 * w.y;
  r.z = g0 * a.z + g1 * s.z + g2 * w.z;
  r.w = g0 * a.w + g1 * s.w + g2 * w.w;
  *(float4*)(xm + (size_t)grow * Cc + c4 * 4) = r;
}

// ---------- launch ----------
extern "C" void kernel_launch(void* const* d_in, const int* in_sizes, int n_in,
                              void* d_out, int out_size, void* d_ws, size_t ws_size,
                              hipStream_t stream) {
  (void)in_sizes; (void)n_in; (void)out_size; (void)ws_size;
  const float* query = (const float*)d_in[0];
  const float* key   = (const float*)d_in[1];
  const float* value = (const float*)d_in[2];
  const float* Wq = (const float*)d_in[3];
  const float* bq = (const float*)d_in[4];
  const float* Wk = (const float*)d_in[5];
  const float* bk = (const float*)d_in[6];
  const float* Wv = (const float*)d_in[7];
  const float* bv = (const float*)d_in[8];
  const float* Wo = (const float*)d_in[9];
  const float* bo = (const float*)d_in[10];
  const float* WKc = (const float*)d_in[11];
  const float* WVc = (const float*)d_in[12];
  const float* Wpe = (const float*)d_in[13];
  const float* Wg = (const float*)d_in[14];
  const float* bg = (const float*)d_in[15];

  size_t off = 0;
  auto alloc = [&](size_t bytes) -> void* {
    void* p = (char*)d_ws + off;
    off += (bytes + 255) & ~(size_t)255;
    return p;
  };
  float* qh    = (float*)alloc((size_t)TROWSc * HDc * 4);
  float* kh    = (float*)alloc((size_t)TROWSc * HDc * 4);
  float* vh    = (float*)alloc((size_t)TROWSc * HDc * 4);
  float* gatep = (float*)alloc((size_t)ROWSc * 3 * 4);
  float* Kcp   = (float*)alloc((size_t)BHc * NBc * HDc * 4);
  float* Vcp   = (float*)alloc((size_t)BHc * NBc * HDc * 4);
  float* ocmp  = (float*)alloc((size_t)TROWSc * HDc * 4);
  float* oslc  = (float*)alloc((size_t)TROWSc * HDc * 4);
  float* owin  = (float*)alloc((size_t)TROWSc * HDc * 4);
  float* xm    = (float*)alloc((size_t)ROWSc * Cc * 4);
  unsigned short* qhb = (unsigned short*)alloc((size_t)TROWSc * HDc * 2);
  unsigned short* khb = (unsigned short*)alloc((size_t)TROWSc * HDc * 2);

  proj_kernel<<<dim3(512), 256, 0, stream>>>(query, Wq, bq, qh, 1);
  proj_kernel<<<dim3(512), 256, 0, stream>>>(key, Wk, bk, kh, 1);
  proj_kernel<<<dim3(512), 256, 0, stream>>>(value, Wv, bv, vh, 1);
  gate_kernel<<<dim3(16), 256, 0, stream>>>(query, Wg, bg, gatep);
  cmpkv_kernel<<<dim3(256), 256, 0, stream>>>(kh, vh, WKc, WVc, Wpe, Kcp, Vcp);
  cmp_attn_kernel<<<dim3(32, 16), 512, 0, stream>>>(qh, Kcp, Vcp, ocmp);
  cvtbf16_kernel<<<dim3(2048), 256, 0, stream>>>(qh, kh, qhb, khb);
  mfma_sel_kernel<<<dim3(128, 16), 512, 0, stream>>>(qhb, khb, qh, kh, vh, oslc);
  win_attn_kernel<<<dim3(32, 16), 512, 0, stream>>>(qh, kh, vh, owin);
  combine_kernel<<<dim3(1024), 256, 0, stream>>>(ocmp, oslc, owin, gatep, xm);
  proj_kernel<<<dim3(512), 256, 0, stream>>>(xm, Wo, bo, (float*)d_out, 0);
}

// Round 11
// 242.948 us; speedup vs baseline: 1.0637x; 1.0255x over previous
//
#include <hip/hip_runtime.h>
#include <math.h>

// NSA attention (round 23: mfma_sel occupancy + LDS-conflict fixes. Round 22
// post-mortem: fused kernel = 92 us ~ sum of parts; counters show 62 KB LDS
// -> 2 blocks/CU (38% occ), VALU 52%, nothing saturated -> phase-B latency
// chains at low occupancy, not panel HBM, were the binding constraint all
// along. Fixes, keeping the VERIFIED r22 machinery byte-identical:
//  1. lp staging tile deleted (-17.4 KB): MFMA quantize byte-stores directly
//     into pnl (same bank pattern as before, measured cheap). LDS 62->44.8KB
//     -> 3 blocks/CU (24 waves, 6/SIMD; VGPR 60 fits).
//  2. phase-B panel read: lane*32 uint4 (16-way bank conflict) -> 8x
//     ds_read_b32 at pnl[row][lane*4 + j*256]: bank = lane%32, conflict-free.
//     Key map key = (i>>2)*256 + lane*4 + (i&3) (bijection; threshold/compact
//     partition-agnostic).
//  3. threshold/compact/recompute/rank-scan/softmax+V verbatim (r21/r22
//     verified; -5 margin superset proof unchanged).
// B=2 L=2048 C=256 H=8 HD=32 BS=16 SK=16 win=+-32.

#define Bc 2
#define Lc 2048
#define Cc 256
#define Hc 8
#define HDc 32
#define BHc 16          // B*H
#define NBc 128         // L/BS
#define ROWSc 4096      // B*L
#define TROWSc 32768    // B*H*L
#define SCALEc 0.17677669529663687f

typedef unsigned long long u64;
typedef __attribute__((ext_vector_type(8))) short short8v;   // 8 bf16
typedef __attribute__((ext_vector_type(4))) float f32x4;

// ---------- helpers ----------

__device__ __forceinline__ float dot32q(const float* qr, const float* kr) {
  const float4* k4 = (const float4*)kr;
  float p0 = 0.f, p1 = 0.f, p2 = 0.f, p3 = 0.f;
#pragma unroll
  for (int j = 0; j < 8; j += 4) {
    float4 a = k4[j], b = k4[j + 1], c = k4[j + 2], e = k4[j + 3];
    p0 += a.x * qr[4 * j + 0] + a.y * qr[4 * j + 1] + a.z * qr[4 * j + 2] + a.w * qr[4 * j + 3];
    p1 += b.x * qr[4 * j + 4] + b.y * qr[4 * j + 5] + b.z * qr[4 * j + 6] + b.w * qr[4 * j + 7];
    p2 += c.x * qr[4 * j + 8] + c.y * qr[4 * j + 9] + c.z * qr[4 * j + 10] + c.w * qr[4 * j + 11];
    p3 += e.x * qr[4 * j + 12] + e.y * qr[4 * j + 13] + e.z * qr[4 * j + 14] + e.w * qr[4 * j + 15];
  }
  return (p0 + p1) + (p2 + p3);
}

__device__ __forceinline__ unsigned short bf16rne(float f) {
  const unsigned u = __float_as_uint(f);
  return (unsigned short)((u + 0x7fffu + ((u >> 16) & 1u)) >> 16);
}

// order-preserving float->int map
__device__ __forceinline__ int f2o(float x) {
  const int i = __float_as_int(x);
  return i >= 0 ? i : (i ^ 0x7fffffff);
}

// ---------- projections ----------
// X(4096,256) @ W(256,256) + bias. headlayout=1: store [b*H+h][l][d]; else [row][c].
__global__ __launch_bounds__(256) void proj_kernel(const float* __restrict__ X,
                                                   const float* __restrict__ W,
                                                   const float* __restrict__ bias,
                                                   float* __restrict__ outp, int headlayout) {
  __shared__ float xs[8 * Cc];
  const int tid = threadIdx.x;
  const int row0 = blockIdx.x * 8;
  {
    const float4* xin = (const float4*)(X + (size_t)row0 * Cc);
    float4* xsv = (float4*)xs;
    xsv[tid] = xin[tid];
    xsv[tid + 256] = xin[tid + 256];
  }
  __syncthreads();
  const int c0 = (tid & 63) * 4;  // 4 consecutive cols
  const int rh = tid >> 6;        // wave id; 2 rows per wave
  float acc[2][4];
#pragma unroll
  for (int r = 0; r < 2; ++r)
#pragma unroll
    for (int c = 0; c < 4; ++c) acc[r][c] = 0.f;

#pragma unroll 4
  for (int d4 = 0; d4 < 64; ++d4) {
    const int d = d4 * 4;
    const float4 w0 = *(const float4*)(W + (size_t)(d + 0) * Cc + c0);
    const float4 w1 = *(const float4*)(W + (size_t)(d + 1) * Cc + c0);
    const float4 w2 = *(const float4*)(W + (size_t)(d + 2) * Cc + c0);
    const float4 w3 = *(const float4*)(W + (size_t)(d + 3) * Cc + c0);
#pragma unroll
    for (int r = 0; r < 2; ++r) {
      const float4 xv = *(const float4*)(xs + (rh * 2 + r) * Cc + d);
      acc[r][0] += xv.x * w0.x + xv.y * w1.x + xv.z * w2.x + xv.w * w3.x;
      acc[r][1] += xv.x * w0.y + xv.y * w1.y + xv.z * w2.y + xv.w * w3.y;
      acc[r][2] += xv.x * w0.z + xv.y * w1.z + xv.z * w2.z + xv.w * w3.z;
      acc[r][3] += xv.x * w0.w + xv.y * w1.w + xv.z * w2.w + xv.w * w3.w;
    }
  }
  const float4 bv = *(const float4*)(bias + c0);
#pragma unroll
  for (int r = 0; r < 2; ++r) {
    const int grow = row0 + rh * 2 + r;
    const float4 o = make_float4(acc[r][0] + bv.x, acc[r][1] + bv.y,
                                 acc[r][2] + bv.z, acc[r][3] + bv.w);
    if (headlayout) {
      const int b = grow >> 11, l = grow & 2047;
      const int h = c0 >> 5, dd = c0 & 31;
      *(float4*)(outp + (((size_t)(b * Hc + h) * Lc + l) * HDc + dd)) = o;
    } else {
      *(float4*)(outp + (size_t)grow * Cc + c0) = o;
    }
  }
}

// gate = sigmoid(query @ Wg + bg), one thread per row
__global__ __launch_bounds__(256) void gate_kernel(const float* __restrict__ query,
                                                   const float* __restrict__ Wg,
                                                   const float* __restrict__ bg,
                                                   float* __restrict__ gatep) {
  const int row = blockIdx.x * 256 + threadIdx.x;
  const float4* x4 = (const float4*)(query + (size_t)row * Cc);
  float a0 = bg[0], a1 = bg[1], a2 = bg[2];
#pragma unroll 8
  for (int d4 = 0; d4 < 64; ++d4) {
    const float4 xv = x4[d4];
    const float* wr = Wg + d4 * 12;
    a0 += xv.x * wr[0] + xv.y * wr[3] + xv.z * wr[6] + xv.w * wr[9];
    a1 += xv.x * wr[1] + xv.y * wr[4] + xv.z * wr[7] + xv.w * wr[10];
    a2 += xv.x * wr[2] + xv.y * wr[5] + xv.z * wr[8] + xv.w * wr[11];
  }
  float* g = gatep + (size_t)row * 3;
  g[0] = 1.f / (1.f + __expf(-a0));
  g[1] = 1.f / (1.f + __expf(-a1));
  g[2] = 1.f / (1.f + __expf(-a2));
}

// ---------- compressed K/V ----------
__global__ __launch_bounds__(256) void cmpkv_kernel(const float* __restrict__ kh,
                                                    const float* __restrict__ vh,
                                                    const float* __restrict__ WKc,
                                                    const float* __restrict__ WVc,
                                                    const float* __restrict__ Wpe,
                                                    float* __restrict__ Kcp,
                                                    float* __restrict__ Vcp) {
  const int idx = blockIdx.x * 256 + threadIdx.x;  // 65536 = bh*128*32
  const int d = idx & 31, n = (idx >> 5) & 127, bh = idx >> 12;
  float pk = 0.f, pv = 0.f;
#pragma unroll
  for (int s = 0; s < 16; ++s) {
    const float pe = Wpe[s * Cc + d];
    pk += pe * WKc[s];
    pv += pe * WVc[s];
  }
  const float* kp = kh + ((size_t)bh * Lc + n * 16) * HDc + d;
  const float* vp = vh + ((size_t)bh * Lc + n * 16) * HDc + d;
  float ak = pk, av = pv;
#pragma unroll
  for (int s = 0; s < 16; ++s) {
    ak += kp[s * HDc] * WKc[s];
    av += vp[s * HDc] * WVc[s];
  }
  Kcp[idx] = ak;
  Vcp[idx] = av;
}

// ---------- compressed attention ----------
__global__ __launch_bounds__(512) void cmp_attn_kernel(const float* __restrict__ qh,
                                                       const float* __restrict__ Kcp,
                                                       const float* __restrict__ Vcp,
                                                       float* __restrict__ ocmp) {
  __shared__ float sc[128][65];
  __shared__ float pm[8][64];
  const int tid = threadIdx.x, lane = tid & 63;
  const int w = __builtin_amdgcn_readfirstlane(tid >> 6);
  const int bh = blockIdx.y;
  const int lrow = blockIdx.x * 64 + lane;
  const float* q = qh + ((size_t)bh * Lc + lrow) * HDc;
  float qr[HDc];
#pragma unroll
  for (int d = 0; d < HDc; ++d) qr[d] = q[d] * SCALEc;
  const float* kcb = Kcp + (size_t)bh * NBc * HDc;
  float pmax = -1e30f;
#pragma unroll
  for (int i = 0; i < 16; ++i) {
    const int key = w * 16 + i;  // uniform
    const float s = dot32q(qr, kcb + (size_t)key * HDc);
    sc[key][lane] = s;
    pmax = fmaxf(pmax, s);
  }
  pm[w][lane] = pmax;
  __syncthreads();

  const int row = tid >> 3;        // 0..63
  const int dg = (tid & 7) * 4;    // dim-group base
  float m = pm[0][row];
#pragma unroll
  for (int i = 1; i < 8; ++i) m = fmaxf(m, pm[i][row]);
  const float* vcb = Vcp + (size_t)bh * NBc * HDc + dg;
  float o0 = 0.f, o1 = 0.f, o2 = 0.f, o3 = 0.f, z = 0.f;
#pragma unroll 4
  for (int key = 0; key < 128; ++key) {
    const float wgt = __expf(sc[key][row] - m);
    z += wgt;
    const float4 v = *(const float4*)(vcb + key * HDc);
    o0 += wgt * v.x; o1 += wgt * v.y; o2 += wgt * v.z; o3 += wgt * v.w;
  }
  const float iz = 1.f / z;
  *(float4*)(ocmp + ((size_t)bh * Lc + blockIdx.x * 64 + row) * HDc + dg) =
      make_float4(o0 * iz, o1 * iz, o2 * iz, o3 * iz);
}

// ---------- f32 -> bf16 (rne) for qh, kh ----------
__global__ __launch_bounds__(256) void cvtbf16_kernel(const float* __restrict__ qh,
                                                      const float* __restrict__ kh,
                                                      unsigned short* __restrict__ qhb,
                                                      unsigned short* __restrict__ khb) {
  const int gid = blockIdx.x * 256 + threadIdx.x;  // 0..524288
  const int half = (TROWSc * HDc) / 4;             // 262144 float4-groups
  const float* src = gid < half ? qh : kh;
  unsigned short* dst = gid < half ? qhb : khb;
  const int i = (gid < half ? gid : gid - half) * 4;
  const float4 v = *(const float4*)(src + i);
  ushort4 o;
  o.x = bf16rne(v.x);
  o.y = bf16rne(v.y);
  o.z = bf16rne(v.z);
  o.w = bf16rne(v.w);
  *(ushort4*)(dst + i) = o;
}

// ---------- fused MFMA screen panel (LDS) + selection ----------
// Grid (128 rowtiles, 16 heads), block 512 = 8 waves. LDS 44.8 KB ->
// 3 blocks/CU.
// Phase A (r19-verified fragments): wave w computes rows [r0,r0+16) x keys
// [w*256,+256) as 2 chunks x 8 MFMA 16x16x32; quantize u8 (monotone) and
// byte-store DIRECTLY into pnl[16][2064]. ONE barrier.
// Phase B (r21-verified): wave w rows {2w, 2w+1}: 8x ds_read_b32 at
// pnl[row][lane*4 + j*256] (bank = lane%32, conflict-free); key map
// key = (i>>2)*256 + lane*4 + (i&3). 8-step ballot threshold (M16q-5,
// provable superset), ballot-compact, exact f32 recompute, 44-bit-ordinal
// rank scan (exact jax (val desc, key asc)), softmax + V gather.
__global__ __launch_bounds__(512) void mfma_sel_kernel(
    const unsigned short* __restrict__ qhb,
    const unsigned short* __restrict__ khb,
    const float* __restrict__ qh,
    const float* __restrict__ kh,
    const float* __restrict__ vh,
    float* __restrict__ oslc) {
  __shared__ unsigned char pnl[16][2064];  // 33,024 B (pad: bank shift 4/row)
  __shared__ float candv[8][16];           // 512 B
  __shared__ unsigned candk[8][128];       // 4 KB
  __shared__ u64 ords[8][128];             // 8 KB
  const int tid = threadIdx.x, lane = tid & 63;
  const int w = __builtin_amdgcn_readfirstlane(tid >> 6);
  const int g = lane >> 4;
  const int mn = lane & 15;
  const int bh = blockIdx.y;
  const int r0 = blockIdx.x * 16;

  // ---- phase A: u8 panel -> LDS (direct byte stores, no staging tile) ----
  const short8v qa =
      *(const short8v*)(qhb + ((size_t)bh * Lc + r0 + mn) * HDc + g * 8);
#pragma unroll
  for (int it = 0; it < 2; ++it) {
    const int k0 = w * 256 + it * 128;
    const unsigned short* kbase = khb + ((size_t)bh * Lc + k0) * HDc + g * 8;
    f32x4 acc0 = {0.f, 0.f, 0.f, 0.f}, acc1 = acc0, acc2 = acc0, acc3 = acc0;
    f32x4 acc4 = acc0, acc5 = acc0, acc6 = acc0, acc7 = acc0;
#define MM(i, dstv)                                                            \
  {                                                                            \
    const short8v kb = *(const short8v*)(kbase + (size_t)((i)*16 + mn) * HDc); \
    dstv = __builtin_amdgcn_mfma_f32_16x16x32_bf16(qa, kb, dstv, 0, 0, 0);     \
  }
    MM(0, acc0) MM(1, acc1) MM(2, acc2) MM(3, acc3)
    MM(4, acc4) MM(5, acc5) MM(6, acc6) MM(7, acc7)
#undef MM
#define QSTORE(t, accv)                                                        \
  {                                                                            \
    _Pragma("unroll") for (int r = 0; r < 4; ++r) {                            \
      const float s = accv[r] * SCALEc;                                        \
      int qi = (int)(s * 16.f + 128.f);                                        \
      qi = qi < 0 ? 0 : (qi > 255 ? 255 : qi);                                 \
      pnl[4 * g + r][k0 + (t)*16 + mn] = (unsigned char)qi;                    \
    }                                                                          \
  }
    QSTORE(0, acc0) QSTORE(1, acc1) QSTORE(2, acc2) QSTORE(3, acc3)
    QSTORE(4, acc4) QSTORE(5, acc5) QSTORE(6, acc6) QSTORE(7, acc7)
#undef QSTORE
  }
  __syncthreads();

  // ---- phase B: selection for rows 2w, 2w+1 ----
#pragma unroll 1
  for (int rr = 0; rr < 2; ++rr) {
    const int row = w * 2 + rr;
    const int l = r0 + row;
    const int r = bh * Lc + l;  // global row

    // 1. 32 u8 from LDS panel (8 conflict-free dword reads), per-lane max
    unsigned wds[8];
#pragma unroll
    for (int j = 0; j < 8; ++j)
      wds[j] = *(const unsigned*)&pnl[row][lane * 4 + j * 256];
    int q[32];
#pragma unroll
    for (int wi = 0; wi < 8; ++wi) {
      q[4 * wi + 0] = (int)(wds[wi] & 255u);
      q[4 * wi + 1] = (int)((wds[wi] >> 8) & 255u);
      q[4 * wi + 2] = (int)((wds[wi] >> 16) & 255u);
      q[4 * wi + 3] = (int)(wds[wi] >> 24);
    }
    int mq = 0;
#pragma unroll
    for (int i = 0; i < 32; ++i) mq = max(mq, q[i]);

    // 2. M16q via 8-step ballot binary search
    int T8 = 0;
#pragma unroll
    for (int b = 7; b >= 0; --b) {
      const int trial = T8 | (1 << b);
      const int c = (int)__popcll(__ballot(mq >= trial));
      if (c >= 16) T8 = trial;  // wave-uniform
    }
    const int thr = T8 - 5;  // margin: bf16 screen err + quant bucket

    // 3. ballot-compact candidate keys (q >= thr); key = (i>>2)*256+lane*4+(i&3)
    candk[w][lane] = 0x7fffffffu;
    candk[w][64 + lane] = 0x7fffffffu;
    __asm__ volatile("s_waitcnt lgkmcnt(0)" ::: "memory");
    int base = 0;
#pragma unroll
    for (int i = 0; i < 32; ++i) {
      const bool p_ = q[i] >= thr;
      const unsigned long long bm_ = __ballot(p_);
      if (bm_) {
        if (p_) {
          const int pos_ =
              base + (int)__builtin_amdgcn_mbcnt_hi(
                         (unsigned)(bm_ >> 32),
                         __builtin_amdgcn_mbcnt_lo((unsigned)bm_, 0u));
          if (pos_ < 128)
            candk[w][pos_] = (unsigned)((i >> 2) * 256 + lane * 4 + (i & 3));
        }
        base += (int)__popcll(bm_);
      }
    }
    const int cnt = base < 128 ? base : 128;  // wave-uniform, >= 16
    __asm__ volatile("s_waitcnt lgkmcnt(0)" ::: "memory");

    // 4. exact f32 dots for slots {lane, lane+64}; 44-bit unique ordinals
    const float* qp = qh + (size_t)r * HDc;
    float qr[HDc];
#pragma unroll
    for (int d = 0; d < HDc; ++d) qr[d] = qp[d] * SCALEc;
    const float* kb = kh + (size_t)bh * Lc * HDc;

    const bool vA = (lane < cnt);
    const bool vB = (64 + lane < cnt);
    const unsigned kA = candk[w][lane];
    const unsigned kB = candk[w][64 + lane];
    const float sA = dot32q(qr, kb + (size_t)(vA ? kA : 0u) * HDc);
    const float sB = dot32q(qr, kb + (size_t)(vB ? kB : 0u) * HDc);
    const u64 ordA =
        vA ? (((u64)((unsigned)f2o(sA) ^ 0x80000000u) << 12) | (u64)(2047u - kA))
           : 0ull;
    const u64 ordB =
        vB ? (((u64)((unsigned)f2o(sB) ^ 0x80000000u) << 12) | (u64)(2047u - kB))
           : 0ull;

    // 5. rank scan (parallel across lanes, no serial chain)
    ords[w][lane] = ordA;
    ords[w][64 + lane] = ordB;
    __asm__ volatile("s_waitcnt lgkmcnt(0)" ::: "memory");
    int rankA = 0, rankB = 0;
#pragma unroll 4
    for (int i = 0; i < cnt; ++i) {  // wave-uniform trip count
      const u64 o = ords[w][i];      // same addr all lanes -> LDS broadcast
      rankA += (o > ordA) ? 1 : 0;
      rankB += (o > ordB) ? 1 : 0;
    }
    if (vA && rankA < 16) {
      candv[w][rankA] = sA;
      candk[w][rankA] = kA;
    }
    if (vB && rankB < 16) {
      candv[w][rankB] = sB;
      candk[w][rankB] = kB;
    }
    __asm__ volatile("s_waitcnt lgkmcnt(0)" ::: "memory");

    // 6. softmax + V gather (order-invariant; mtop = fmax chain)
    float mtop = candv[w][0];
#pragma unroll
    for (int i = 1; i < 16; ++i) mtop = fmaxf(mtop, candv[w][i]);
    const int d = lane & 31;
    const float* vb = vh + (size_t)bh * Lc * HDc + d;
    float z = 0.f, oacc = 0.f;
#pragma unroll
    for (int i = 0; i < 16; ++i) {
      const float w_ = __expf(candv[w][i] - mtop);
      z += w_;
      oacc += w_ * vb[(size_t)candk[w][i] * HDc];
    }
    if (lane < 32) oslc[((size_t)bh * Lc + l) * HDc + d] = oacc / z;
  }
}

// ---------- window attention (±32 band) ----------
__global__ __launch_bounds__(512) void win_attn_kernel(const float* __restrict__ qh,
                                                       const float* __restrict__ kh,
                                                       const float* __restrict__ vh,
                                                       float* __restrict__ owin) {
  __shared__ float sc[128][65];
  __shared__ float pm[8][64];
  const int tid = threadIdx.x, lane = tid & 63;
  const int w = __builtin_amdgcn_readfirstlane(tid >> 6);
  const int bh = blockIdx.y;
  const int l0 = blockIdx.x * 64;
  const int lrow = l0 + lane;
  const float* q = qh + ((size_t)bh * Lc + lrow) * HDc;
  float qr[HDc];
#pragma unroll
  for (int d = 0; d < HDc; ++d) qr[d] = q[d] * SCALEc;
  const float* kb = kh + (size_t)bh * Lc * HDc;
  float pmax = -1e30f;
#pragma unroll
  for (int i = 0; i < 16; ++i) {
    const int j = w * 16 + i;            // 0..127 (uniform)
    const int key = l0 - 32 + j;         // absolute key (uniform)
    const int keyc = min(max(key, 0), Lc - 1);  // uniform clamp for the load
    float s = dot32q(qr, kb + (size_t)keyc * HDc);
    const int delta = key - lrow;        // lane-varying
    const bool ok = (key >= 0) && (key < Lc) && (delta >= -32) && (delta <= 32);
    s = ok ? s : -1e30f;
    sc[j][lane] = s;
    pmax = fmaxf(pmax, s);
  }
  pm[w][lane] = pmax;
  __syncthreads();

  const int row = tid >> 3;
  const int dg = (tid & 7) * 4;
  float m = pm[0][row];
#pragma unroll
  for (int i = 1; i < 8; ++i) m = fmaxf(m, pm[i][row]);
  const float* vb = vh + (size_t)bh * Lc * HDc + dg;
  float o0 = 0.f, o1 = 0.f, o2 = 0.f, o3 = 0.f, z = 0.f;
#pragma unroll 4
  for (int j = 0; j < 128; ++j) {
    const float wgt = __expf(sc[j][row] - m);  // 0 for masked entries
    z += wgt;
    const int keyc = min(max(l0 - 32 + j, 0), Lc - 1);
    const float4 v = *(const float4*)(vb + (size_t)keyc * HDc);
    o0 += wgt * v.x; o1 += wgt * v.y; o2 += wgt * v.z; o3 += wgt * v.w;
  }
  const float iz = 1.f / z;
  *(float4*)(owin + ((size_t)bh * Lc + l0 + row) * HDc + dg) =
      make_float4(o0 * iz, o1 * iz, o2 * iz, o3 * iz);
}

// ---------- gated combine into merged (B,L,C) ----------
__global__ __launch_bounds__(256) void combine_kernel(const float* __restrict__ ocmp,
                                                      const float* __restrict__ oslc,
                                                      const float* __restrict__ owin,
                                                      const float* __restrict__ gatep,
                                                      float* __restrict__ xm) {
  const int idx = blockIdx.x * 256 + threadIdx.x;  // 4096 rows * 64 float4-groups
  const int c4 = idx & 63, grow = idx >> 6;
  const int b = grow >> 11, l = grow & 2047;
  const int h = c4 >> 3, d4 = (c4 & 7) * 4;
  const size_t hoff = (((size_t)(b * Hc + h) * Lc + l)) * HDc + d4;
  const float g0 = gatep[(size_t)grow * 3 + 0];
  const float g1 = gatep[(size_t)grow * 3 + 1];
  const float g2 = gatep[(size_t)grow * 3 + 2];
  const float4 a = *(const float4*)(ocmp + hoff);
  const float4 s = *(const float4*)(oslc + hoff);
  const float4 w = *(const float4*)(owin + hoff);
  float4 r;
  r.x = g0 * a.x + g1 * s.x + g2 * w.x;
  r.y = g0 * a.y + g1 * s.y + g2 * w.y;
  r.z = g0 * a.z + g1 * s.z + g2 * w.z;
  r.w = g0 * a.w + g1 * s.w + g2 * w.w;
  *(float4*)(xm + (size_t)grow * Cc + c4 * 4) = r;
}

// ---------- launch ----------
extern "C" void kernel_launch(void* const* d_in, const int* in_sizes, int n_in,
                              void* d_out, int out_size, void* d_ws, size_t ws_size,
                              hipStream_t stream) {
  (void)in_sizes; (void)n_in; (void)out_size; (void)ws_size;
  const float* query = (const float*)d_in[0];
  const float* key   = (const float*)d_in[1];
  const float* value = (const float*)d_in[2];
  const float* Wq = (const float*)d_in[3];
  const float* bq = (const float*)d_in[4];
  const float* Wk = (const float*)d_in[5];
  const float* bk = (const float*)d_in[6];
  const float* Wv = (const float*)d_in[7];
  const float* bv = (const float*)d_in[8];
  const float* Wo = (const float*)d_in[9];
  const float* bo = (const float*)d_in[10];
  const float* WKc = (const float*)d_in[11];
  const float* WVc = (const float*)d_in[12];
  const float* Wpe = (const float*)d_in[13];
  const float* Wg = (const float*)d_in[14];
  const float* bg = (const float*)d_in[15];

  size_t off = 0;
  auto alloc = [&](size_t bytes) -> void* {
    void* p = (char*)d_ws + off;
    off += (bytes + 255) & ~(size_t)255;
    return p;
  };
  float* qh    = (float*)alloc((size_t)TROWSc * HDc * 4);
  float* kh    = (float*)alloc((size_t)TROWSc * HDc * 4);
  float* vh    = (float*)alloc((size_t)TROWSc * HDc * 4);
  float* gatep = (float*)alloc((size_t)ROWSc * 3 * 4);
  float* Kcp   = (float*)alloc((size_t)BHc * NBc * HDc * 4);
  float* Vcp   = (float*)alloc((size_t)BHc * NBc * HDc * 4);
  float* ocmp  = (float*)alloc((size_t)TROWSc * HDc * 4);
  float* oslc  = (float*)alloc((size_t)TROWSc * HDc * 4);
  float* owin  = (float*)alloc((size_t)TROWSc * HDc * 4);
  float* xm    = (float*)alloc((size_t)ROWSc * Cc * 4);
  unsigned short* qhb = (unsigned short*)alloc((size_t)TROWSc * HDc * 2);
  unsigned short* khb = (unsigned short*)alloc((size_t)TROWSc * HDc * 2);

  proj_kernel<<<dim3(512), 256, 0, stream>>>(query, Wq, bq, qh, 1);
  proj_kernel<<<dim3(512), 256, 0, stream>>>(key, Wk, bk, kh, 1);
  proj_kernel<<<dim3(512), 256, 0, stream>>>(value, Wv, bv, vh, 1);
  gate_kernel<<<dim3(16), 256, 0, stream>>>(query, Wg, bg, gatep);
  cmpkv_kernel<<<dim3(256), 256, 0, stream>>>(kh, vh, WKc, WVc, Wpe, Kcp, Vcp);
  cmp_attn_kernel<<<dim3(32, 16), 512, 0, stream>>>(qh, Kcp, Vcp, ocmp);
  cvtbf16_kernel<<<dim3(2048), 256, 0, stream>>>(qh, kh, qhb, khb);
  mfma_sel_kernel<<<dim3(128, 16), 512, 0, stream>>>(qhb, khb, qh, kh, vh, oslc);
  win_attn_kernel<<<dim3(32, 16), 512, 0, stream>>>(qh, kh, vh, owin);
  combine_kernel<<<dim3(1024), 256, 0, stream>>>(ocmp, oslc, owin, gatep, xm);
  proj_kernel<<<dim3(512), 256, 0, stream>>>(xm, Wo, bo, (float*)d_out, 0);
}